// Round 1
// baseline (8156.848 us; speedup 1.0000x reference)
//
#include <hip/hip_runtime.h>

// TransportKernel: loss = ||k_ZZ||_F^2 - 2||k_ZY||_F^2 + 0.01 * tr(Z^T (K_XX+1e-3 I)^{-1} Z)
// Strategy: fused exp-sum for the Frobenius part; Cholesky A=LL^T and
// tr(Z^T A^{-1} Z) = ||L^{-1} Z||_F^2 (forward solve only) for the reg part.

#define NN   4096
#define LDA  4100            // +4 pad: breaks 16KB power-of-2 row stride, keeps 16B alignment
#define NB   64
#define NSTEP (NN/NB)

#define OFF_LINVT ((size_t)NN*LDA)          // 64x64 transposed diag-inverse
#define OFF_W     (OFF_LINVT + NB*NB)       // W: 4096 x 4 solve buffer
#define OFF_ACC_B ((OFF_W + (size_t)NN*4)*4)// byte offset of double accumulators

// ------------------------------------------------------------------
// A[i][j] = exp(-||x_i-x_j||^2 / 2) + 0.001*(i==j)
__global__ void k_build_A(const float* __restrict__ X, float* __restrict__ A){
    const int i  = blockIdx.y;
    const int j0 = (blockIdx.x*256 + threadIdx.x)*4;
    const float4 xi = *(const float4*)(X + (size_t)i*4);
    float out[4];
#pragma unroll
    for (int s=0;s<4;s++){
        const float4 xj = *(const float4*)(X + (size_t)(j0+s)*4);
        float d0=xi.x-xj.x, d1=xi.y-xj.y, d2=xi.z-xj.z, d3=xi.w-xj.w;
        float sq = d0*d0+d1*d1+d2*d2+d3*d3;
        float v  = __expf(-0.5f*sq);
        if (i == j0+s) v += 0.001f;
        out[s]=v;
    }
    *(float4*)(A + (size_t)i*LDA + j0) = make_float4(out[0],out[1],out[2],out[3]);
}

// ------------------------------------------------------------------
// Factor 64x64 diag block (lower Cholesky) in LDS, write L back,
// and produce LinvT[t][j] = (L11^{-1})[j][t] for the GEMM-style TRSM.
__global__ void k_chol_diag_inv(float* __restrict__ A, float* __restrict__ LinvT, int k){
    __shared__ float La[NB][NB+1];
    __shared__ float Li[NB][NB+1];
    const int tid = threadIdx.x;

    for (int idx=tid; idx<NB*16; idx+=256){
        int r=idx>>4, q=idx&15;
        float4 v = *(const float4*)(A + (size_t)(k+r)*LDA + k + q*4);
        La[r][q*4+0]=v.x; La[r][q*4+1]=v.y; La[r][q*4+2]=v.z; La[r][q*4+3]=v.w;
    }
    __syncthreads();

    for (int j=0;j<NB;j++){
        if (tid==0) La[j][j] = sqrtf(La[j][j]);
        __syncthreads();
        if (tid>j && tid<NB) La[tid][j] /= La[j][j];
        __syncthreads();
        {
            const int i0 = tid & 63, g = tid >> 6;
            for (int c=j+1+g; c<NB; c+=4)
                if (i0>=c) La[i0][c] -= La[i0][j]*La[c][j];
        }
        __syncthreads();
    }

    // write factored block back (upper stays as original values; never read)
    for (int idx=tid; idx<NB*NB; idx+=256){
        int r=idx>>6, c=idx&63;
        A[(size_t)(k+r)*LDA + k + c] = La[r][c];
    }
    // zero strict upper of Li (disjoint from solver writes below -> no barrier needed)
    for (int idx=tid; idx<NB*NB; idx+=256){
        int r=idx>>6, c=idx&63;
        if (r<c) Li[r][c]=0.f;
    }
    // forward substitution, 4 lanes per column, wave-local (no barriers)
    {
        const int c = tid>>2, g = tid&3;
        for (int j=c;j<NB;j++){
            float part = 0.f;
            for (int t=c+g; t<j; t+=4) part += La[j][t]*Li[t][c];
            part += __shfl_xor(part,1);
            part += __shfl_xor(part,2);
            float x = ((j==c?1.f:0.f) - part)/La[j][j];
            if (g==0) Li[j][c]=x;
        }
    }
    __syncthreads();
    for (int idx=tid; idx<NB*NB; idx+=256){
        int t=idx>>6, j=idx&63;
        LinvT[t*NB + j] = Li[j][t];
    }
}

// ------------------------------------------------------------------
// Panel TRSM as GEMM: L21 = A21 * L11^{-T};  new[r][j] = sum_t old[r][t]*Linv[j][t]
__global__ void k_trsm(float* __restrict__ A, const float* __restrict__ LinvT, int k){
    __shared__ float PoT[NB][NB+4];  // [t][r]
    __shared__ float LiT[NB][NB+4];  // [t][j]
    const int tid=threadIdx.x;
    const int r0 = k + NB + blockIdx.x*NB;

    for (int idx=tid; idx<NB*16; idx+=256){
        int r=idx>>4, q=idx&15;
        float4 v = *(const float4*)(A + (size_t)(r0+r)*LDA + k + q*4);
        PoT[q*4+0][r]=v.x; PoT[q*4+1][r]=v.y; PoT[q*4+2][r]=v.z; PoT[q*4+3][r]=v.w;
    }
    for (int idx=tid; idx<NB*16; idx+=256){
        int t=idx>>4, q=idx&15;
        float4 v = *(const float4*)(LinvT + t*NB + q*4);
        *(float4*)&LiT[t][q*4] = v;
    }
    __syncthreads();

    const int tx=tid&15, ty=tid>>4;
    float acc[4][4]={};
#pragma unroll 8
    for (int t=0;t<NB;t++){
        float4 a = *(float4*)&PoT[t][ty*4];
        float4 b = *(float4*)&LiT[t][tx*4];
        acc[0][0]+=a.x*b.x; acc[0][1]+=a.x*b.y; acc[0][2]+=a.x*b.z; acc[0][3]+=a.x*b.w;
        acc[1][0]+=a.y*b.x; acc[1][1]+=a.y*b.y; acc[1][2]+=a.y*b.z; acc[1][3]+=a.y*b.w;
        acc[2][0]+=a.z*b.x; acc[2][1]+=a.z*b.y; acc[2][2]+=a.z*b.z; acc[2][3]+=a.z*b.w;
        acc[3][0]+=a.w*b.x; acc[3][1]+=a.w*b.y; acc[3][2]+=a.w*b.z; acc[3][3]+=a.w*b.w;
    }
#pragma unroll
    for (int i2=0;i2<4;i2++)
        *(float4*)(A + (size_t)(r0+ty*4+i2)*LDA + k + tx*4) =
            make_float4(acc[i2][0],acc[i2][1],acc[i2][2],acc[i2][3]);
}

// ------------------------------------------------------------------
// Trailing update: A22 -= P P^T, lower-triangle 64x64 tiles.
__global__ void k_syrk(float* __restrict__ A, int k){
    __shared__ float PaT[NB][NB+4];
    __shared__ float PbT[NB][NB+4];
    const int tid=threadIdx.x;
    const int t = blockIdx.x;
    int bi = (int)((sqrtf(8.f*(float)t+1.f)-1.f)*0.5f);
    while ((bi+1)*(bi+2)/2 <= t) ++bi;
    while (bi*(bi+1)/2 > t) --bi;
    const int bj = t - bi*(bi+1)/2;
    const int r0 = k+NB+bi*NB, c0 = k+NB+bj*NB;

    for (int idx=tid; idx<NB*16; idx+=256){
        int r=idx>>4, q=idx&15;
        float4 v = *(const float4*)(A + (size_t)(r0+r)*LDA + k + q*4);
        PaT[q*4+0][r]=v.x; PaT[q*4+1][r]=v.y; PaT[q*4+2][r]=v.z; PaT[q*4+3][r]=v.w;
        float4 w = *(const float4*)(A + (size_t)(c0+r)*LDA + k + q*4);
        PbT[q*4+0][r]=w.x; PbT[q*4+1][r]=w.y; PbT[q*4+2][r]=w.z; PbT[q*4+3][r]=w.w;
    }
    __syncthreads();

    const int tx=tid&15, ty=tid>>4;
    float acc[4][4]={};
#pragma unroll 8
    for (int tt=0;tt<NB;tt++){
        float4 a = *(float4*)&PaT[tt][ty*4];
        float4 b = *(float4*)&PbT[tt][tx*4];
        acc[0][0]+=a.x*b.x; acc[0][1]+=a.x*b.y; acc[0][2]+=a.x*b.z; acc[0][3]+=a.x*b.w;
        acc[1][0]+=a.y*b.x; acc[1][1]+=a.y*b.y; acc[1][2]+=a.y*b.z; acc[1][3]+=a.y*b.w;
        acc[2][0]+=a.z*b.x; acc[2][1]+=a.z*b.y; acc[2][2]+=a.z*b.z; acc[2][3]+=a.z*b.w;
        acc[3][0]+=a.w*b.x; acc[3][1]+=a.w*b.y; acc[3][2]+=a.w*b.z; acc[3][3]+=a.w*b.w;
    }
#pragma unroll
    for (int i2=0;i2<4;i2++){
        float* p = A + (size_t)(r0+ty*4+i2)*LDA + c0 + tx*4;
        float4 cv = *(float4*)p;
        cv.x-=acc[i2][0]; cv.y-=acc[i2][1]; cv.z-=acc[i2][2]; cv.w-=acc[i2][3];
        *(float4*)p = cv;
    }
}

// ------------------------------------------------------------------
// Forward solve L V = Z, pipelined: kernel s updates all remaining row-blocks
// against the block solved in kernel s-1, then block 0 solves diag block s.
// One wave per 64-row block.
__global__ void k_fsolve(const float* __restrict__ A, float* __restrict__ W, int s){
    __shared__ float Lb[NB][NB+5];
    __shared__ float Wp[NB][5];
    const int lane = threadIdx.x;          // blockDim = 64
    const int tb = s + blockIdx.x;
    const int r0 = tb*NB;
    float4 wv = *(const float4*)(W + (size_t)r0*4 + lane*4);
    float w0=wv.x,w1=wv.y,w2=wv.z,w3=wv.w;

    if (s>0){
        const int c0=(s-1)*NB;
        for (int idx=lane; idx<NB*16; idx+=64){
            int r=idx>>4,q=idx&15;
            float4 v = *(const float4*)(A + (size_t)(r0+r)*LDA + c0 + q*4);
            Lb[r][q*4+0]=v.x; Lb[r][q*4+1]=v.y; Lb[r][q*4+2]=v.z; Lb[r][q*4+3]=v.w;
        }
        float4 pv = *(const float4*)(W + (size_t)c0*4 + lane*4);
        Wp[lane][0]=pv.x; Wp[lane][1]=pv.y; Wp[lane][2]=pv.z; Wp[lane][3]=pv.w;
        __syncthreads();
        float a0=0.f,a1=0.f,a2=0.f,a3=0.f;
        for (int tt=0;tt<NB;tt++){
            float l = Lb[lane][tt];
            a0 += l*Wp[tt][0]; a1 += l*Wp[tt][1]; a2 += l*Wp[tt][2]; a3 += l*Wp[tt][3];
        }
        w0-=a0; w1-=a1; w2-=a2; w3-=a3;
        __syncthreads();
    }
    if (blockIdx.x==0){
        for (int idx=lane; idx<NB*16; idx+=64){
            int r=idx>>4,q=idx&15;
            float4 v = *(const float4*)(A + (size_t)(r0+r)*LDA + r0 + q*4);
            Lb[r][q*4+0]=v.x; Lb[r][q*4+1]=v.y; Lb[r][q*4+2]=v.z; Lb[r][q*4+3]=v.w;
        }
        __syncthreads();
        const float dinv = 1.f/Lb[lane][lane];
        for (int j=0;j<NB;j++){
            if (lane==j){ w0*=dinv; w1*=dinv; w2*=dinv; w3*=dinv; }
            float b0=__shfl(w0,j), b1=__shfl(w1,j), b2=__shfl(w2,j), b3=__shfl(w3,j);
            float lij = Lb[lane][j];
            if (lane>j){ w0-=lij*b0; w1-=lij*b1; w2-=lij*b2; w3-=lij*b3; }
        }
    }
    *(float4*)(W + (size_t)r0*4 + lane*4) = make_float4(w0,w1,w2,w3);
}

// ------------------------------------------------------------------
// loss_fit = sum exp(-||z_i-z_j||^2) - 2 sum exp(-||z_i-y_j||^2)   (fp64 accum)
__global__ void k_lossfit(const float* __restrict__ Z, const float* __restrict__ Y,
                          double* __restrict__ acc){
    const int tid=threadIdx.x;
    const int i0=blockIdx.x*8;
    double s=0.0;
    for (int ii=0;ii<8;ii++){
        const float4 zi = *(const float4*)(Z + (size_t)(i0+ii)*4);
        for (int j=tid;j<NN;j+=256){
            float4 zj = *(const float4*)(Z + (size_t)j*4);
            float4 yj = *(const float4*)(Y + (size_t)j*4);
            float d0=zi.x-zj.x, d1=zi.y-zj.y, d2=zi.z-zj.z, d3=zi.w-zj.w;
            float dzz = d0*d0+d1*d1+d2*d2+d3*d3;
            d0=zi.x-yj.x; d1=zi.y-yj.y; d2=zi.z-yj.z; d3=zi.w-yj.w;
            float dzy = d0*d0+d1*d1+d2*d2+d3*d3;
            s += (double)(__expf(-dzz) - 2.f*__expf(-dzy));
        }
    }
    for (int o=32;o;o>>=1) s += __shfl_down(s,o);
    __shared__ double ps[4];
    if ((tid&63)==0) ps[tid>>6]=s;
    __syncthreads();
    if (tid==0) atomicAdd(acc, ps[0]+ps[1]+ps[2]+ps[3]);
}

__global__ void k_zero(double* acc){ if (threadIdx.x==0) acc[0]=0.0; }

__global__ void k_copyZ(const float* __restrict__ Z, float* __restrict__ W){
    const int i = blockIdx.x*256+threadIdx.x;
    ((float4*)W)[i] = ((const float4*)Z)[i];
}

__global__ void k_finish(const float* __restrict__ W, const double* __restrict__ acc,
                         float* __restrict__ out){
    const int tid=threadIdx.x;
    double s=0.0;
    for (int r=tid;r<NN;r+=256){
        float4 v=*(const float4*)(W+(size_t)r*4);
        s += (double)v.x*v.x+(double)v.y*v.y+(double)v.z*v.z+(double)v.w*v.w;
    }
    for (int o=32;o;o>>=1) s += __shfl_down(s,o);
    __shared__ double ps[4];
    if ((tid&63)==0) ps[tid>>6]=s;
    __syncthreads();
    if (tid==0) out[0] = (float)(acc[0] + 0.01*(ps[0]+ps[1]+ps[2]+ps[3]));
}

// ------------------------------------------------------------------
extern "C" void kernel_launch(void* const* d_in, const int* in_sizes, int n_in,
                              void* d_out, int out_size, void* d_ws, size_t ws_size,
                              hipStream_t stream){
    const float* X=(const float*)d_in[0];
    const float* Y=(const float*)d_in[1];
    const float* Z=(const float*)d_in[2];
    float* ws    = (float*)d_ws;
    float* A     = ws;
    float* LinvT = ws + OFF_LINVT;
    float* W     = ws + OFF_W;
    double* acc  = (double*)((char*)d_ws + OFF_ACC_B);

    if (ws_size < OFF_ACC_B + 64) return;   // loud failure: output stays poisoned

    k_zero   <<<1,64,0,stream>>>(acc);
    k_lossfit<<<512,256,0,stream>>>(Z,Y,acc);
    k_build_A<<<dim3(NN/1024,NN),256,0,stream>>>(X,A);

    for (int k=0;k<NN;k+=NB){
        k_chol_diag_inv<<<1,256,0,stream>>>(A,LinvT,k);
        const int M = NN-k-NB;
        if (M>0){
            k_trsm<<<M/NB,256,0,stream>>>(A,LinvT,k);
            const int T = M/NB;
            k_syrk<<<T*(T+1)/2,256,0,stream>>>(A,k);
        }
    }
    k_copyZ<<<16,256,0,stream>>>(Z,W);
    for (int s=0;s<NSTEP;s++) k_fsolve<<<NSTEP-s,64,0,stream>>>(A,W,s);
    k_finish<<<1,256,0,stream>>>(W,acc,(float*)d_out);
}

// Round 2
// 3491.994 us; speedup vs baseline: 2.3359x; 2.3359x over previous
//
#include <hip/hip_runtime.h>

// TransportKernel: loss = ||k_ZZ||_F^2 - 2||k_ZY||_F^2 + 0.01 * tr(Z^T (K_XX+1e-3 I)^{-1} Z)
// Cholesky A=LL^T, tr = ||L^{-1}Z||_F^2 (forward solve only).
// Per step s: [k_trsm2: panel substitution-TRSM + W_s diag-solve block]
//             [k_step : 128x128 SYRK tiles + fused chol(s+1) block + W panel-updates]

#define NN   4096
#define LDA  4100
#define OFF_W ((size_t)NN*LDA)
#define OFF_ACC_B ((OFF_W + (size_t)NN*4)*4)

__device__ __forceinline__ float rdlane(float v, int l){
    return __int_as_float(__builtin_amdgcn_readlane(__float_as_int(v), l));
}

// ------------------------------------------------------------------
// A[i][j] = exp(-||x_i-x_j||^2 / 2) + 0.001*(i==j)
__global__ void k_build_A(const float* __restrict__ X, float* __restrict__ A){
    const int i  = blockIdx.y;
    const int j0 = (blockIdx.x*256 + threadIdx.x)*4;
    const float4 xi = *(const float4*)(X + (size_t)i*4);
    float out[4];
#pragma unroll
    for (int s=0;s<4;s++){
        const float4 xj = *(const float4*)(X + (size_t)(j0+s)*4);
        float d0=xi.x-xj.x, d1=xi.y-xj.y, d2=xi.z-xj.z, d3=xi.w-xj.w;
        float sq = d0*d0+d1*d1+d2*d2+d3*d3;
        float v  = __expf(-0.5f*sq);
        if (i == j0+s) v += 0.001f;
        out[s]=v;
    }
    *(float4*)(A + (size_t)i*LDA + j0) = make_float4(out[0],out[1],out[2],out[3]);
}

// ------------------------------------------------------------------
// Single-wave register Cholesky of the 64x64 matrix in LDS Dm (stride 68).
// lane = row. Writes L (lower valid; upper garbage, never read) to A at (k2,k2).
__device__ void wave_chol64(const float* Dm, float* __restrict__ A, int k2){
    const int lane = threadIdx.x & 63;
    float row[64];
#pragma unroll
    for (int q=0;q<16;q++){
        float4 v = *(const float4*)(Dm + lane*68 + q*4);
        row[q*4]=v.x; row[q*4+1]=v.y; row[q*4+2]=v.z; row[q*4+3]=v.w;
    }
#pragma unroll
    for (int j=0;j<64;j++){
        float d  = rdlane(row[j], j);
        float sd = sqrtf(d);
        float inv= 1.0f/sd;
        float v  = (lane==j)? sd : row[j]*inv;
        row[j] = v;
#pragma unroll
        for (int c=j+1;c<64;c++){
            float lc = rdlane(v, c);
            row[c] -= v*lc;
        }
    }
#pragma unroll
    for (int q=0;q<16;q++)
        *(float4*)(A + (size_t)(k2+lane)*LDA + k2 + q*4) =
            make_float4(row[q*4],row[q*4+1],row[q*4+2],row[q*4+3]);
}

// ------------------------------------------------------------------
// Fused trailing-update launch for step s (s=-1: chol(0) only, grid=1):
//  block 0              : rank-64 update of diag block (s+1) + in-register chol
//  blocks 1..nT2        : 128x128 SYRK tiles over trailing lower triangle
//  blocks nT2+1..nT2+T  : W[r] -= L[r,s] * W_s  panel updates
__global__ __launch_bounds__(256) void k_step(float* __restrict__ A, float* __restrict__ W,
                                              const float* __restrict__ Z, int s){
    __shared__ float S[8704];
    const int tid = threadIdx.x;
    const int bid = blockIdx.x;
    const int k2   = (s+1)*64;
    const int T    = 63 - s;
    const int T2   = (T+1)>>1;
    const int nT2  = T2*(T2+1)/2;
    const int kcol = s*64;

    if (bid == 0){
        float* P  = S;            // [64][68] transposed panel: P[t][r]
        float* Dm = S + 4352;     // [64][68]
        if (s >= 0){
#pragma unroll
            for (int it=0; it<4; ++it){
                int idx = tid + it*256;
                int r = idx>>4, q = idx&15;
                float4 v = *(const float4*)(A + (size_t)(k2+r)*LDA + kcol + q*4);
                P[(q*4+0)*68+r]=v.x; P[(q*4+1)*68+r]=v.y;
                P[(q*4+2)*68+r]=v.z; P[(q*4+3)*68+r]=v.w;
            }
            __syncthreads();
            const int tx = tid&15, ty = tid>>4;
            float acc[4][4]={};
#pragma unroll 8
            for (int t=0;t<64;t++){
                float4 a = *(const float4*)&P[t*68 + ty*4];
                float4 b = *(const float4*)&P[t*68 + tx*4];
                acc[0][0]+=a.x*b.x; acc[0][1]+=a.x*b.y; acc[0][2]+=a.x*b.z; acc[0][3]+=a.x*b.w;
                acc[1][0]+=a.y*b.x; acc[1][1]+=a.y*b.y; acc[1][2]+=a.y*b.z; acc[1][3]+=a.y*b.w;
                acc[2][0]+=a.z*b.x; acc[2][1]+=a.z*b.y; acc[2][2]+=a.z*b.z; acc[2][3]+=a.z*b.w;
                acc[3][0]+=a.w*b.x; acc[3][1]+=a.w*b.y; acc[3][2]+=a.w*b.z; acc[3][3]+=a.w*b.w;
            }
#pragma unroll
            for (int i=0;i<4;i++){
                float4 c = *(const float4*)(A + (size_t)(k2+ty*4+i)*LDA + k2 + tx*4);
                c.x-=acc[i][0]; c.y-=acc[i][1]; c.z-=acc[i][2]; c.w-=acc[i][3];
                *(float4*)&Dm[(ty*4+i)*68 + tx*4] = c;
            }
        } else {
#pragma unroll
            for (int it=0; it<4; ++it){
                int idx = tid + it*256;
                int r = idx>>4, q = idx&15;
                float4 v = *(const float4*)(A + (size_t)(k2+r)*LDA + k2 + q*4);
                *(float4*)&Dm[r*68 + q*4] = v;
            }
        }
        __syncthreads();
        if (tid < 64) wave_chol64(Dm, A, k2);
    } else if (bid <= nT2){
        // ---------- 128x128 SYRK tile, k-split 2x32 ----------
        int t2 = bid-1;
        int bi = (int)((sqrtf(8.f*(float)t2+1.f)-1.f)*0.5f);
        while ((bi+1)*(bi+2)/2 <= t2) ++bi;
        while (bi*(bi+1)/2 > t2) --bi;
        const int bj = t2 - bi*(bi+1)/2;
        const int r0 = k2 + bi*128, c0 = k2 + bj*128;
        const int diag = (bi==bj);
        float* Sa = S;
        float* Sb = diag ? S : (S + 4224);
        const int tx = tid&15, ty = tid>>4;
        float acc[8][8]={};
        for (int kk=0; kk<2; ++kk){
            const int kb = kcol + kk*32;
#pragma unroll
            for (int it=0; it<4; ++it){
                int idx = tid + it*256;
                int row = idx>>3, q = idx&7;
                int rl = r0+row; if (rl>4095) rl=4095;
                float4 v = *(const float4*)(A + (size_t)rl*LDA + kb + q*4);
                Sa[(q*4+0)*132+row]=v.x; Sa[(q*4+1)*132+row]=v.y;
                Sa[(q*4+2)*132+row]=v.z; Sa[(q*4+3)*132+row]=v.w;
            }
            if (!diag){
#pragma unroll
                for (int it=0; it<4; ++it){
                    int idx = tid + it*256;
                    int row = idx>>3, q = idx&7;
                    int cl = c0+row; if (cl>4095) cl=4095;
                    float4 v = *(const float4*)(A + (size_t)cl*LDA + kb + q*4);
                    Sb[(q*4+0)*132+row]=v.x; Sb[(q*4+1)*132+row]=v.y;
                    Sb[(q*4+2)*132+row]=v.z; Sb[(q*4+3)*132+row]=v.w;
                }
            }
            __syncthreads();
#pragma unroll 4
            for (int t=0;t<32;t++){
                float4 a0 = *(const float4*)&Sa[t*132 + ty*8];
                float4 a1 = *(const float4*)&Sa[t*132 + ty*8 + 4];
                float4 b0 = *(const float4*)&Sb[t*132 + tx*8];
                float4 b1 = *(const float4*)&Sb[t*132 + tx*8 + 4];
                float av[8]={a0.x,a0.y,a0.z,a0.w,a1.x,a1.y,a1.z,a1.w};
                float bv[8]={b0.x,b0.y,b0.z,b0.w,b1.x,b1.y,b1.z,b1.w};
#pragma unroll
                for (int i=0;i<8;i++)
#pragma unroll
                    for (int j=0;j<8;j++) acc[i][j] += av[i]*bv[j];
            }
            __syncthreads();
        }
        // subtract-store with guards (bounds + chol quadrant owned by block 0)
#pragma unroll
        for (int i=0;i<8;i++){
            const int r = r0 + ty*8 + i;
            if (r > 4095) continue;
#pragma unroll
            for (int jq=0;jq<2;jq++){
                const int c = c0 + tx*8 + jq*4;
                if (c > 4095) continue;
                if (r < k2+64 && c < k2+64) continue;
                float* p = A + (size_t)r*LDA + c;
                float4 cv = *(float4*)p;
                cv.x -= acc[i][jq*4+0]; cv.y -= acc[i][jq*4+1];
                cv.z -= acc[i][jq*4+2]; cv.w -= acc[i][jq*4+3];
                *(float4*)p = cv;
            }
        }
    } else {
        // ---------- W panel update: W[rrow..] -= L[rrow.., kcol..] * W_s ----------
        const int wu = bid - 1 - nT2;
        const int rrow = k2 + wu*64;
        float* Lt = S;          // [64][68] row-major
        float* Ws = S + 4352;   // [64][4]
#pragma unroll
        for (int it=0; it<4; ++it){
            int idx = tid + it*256;
            int r = idx>>4, q = idx&15;
            float4 v = *(const float4*)(A + (size_t)(rrow+r)*LDA + kcol + q*4);
            *(float4*)&Lt[r*68 + q*4] = v;
        }
        if (tid < 64){
            float4 v = *(const float4*)(W + (size_t)(kcol+tid)*4);
            *(float4*)&Ws[tid*4] = v;
        }
        __syncthreads();
        if (tid < 64){
            const float* wsrc = (s==0) ? (Z + (size_t)(rrow+tid)*4) : (W + (size_t)(rrow+tid)*4);
            float4 w = *(const float4*)wsrc;
#pragma unroll 8
            for (int t=0;t<64;t++){
                float l = Lt[tid*68 + t];
                float4 x = *(const float4*)&Ws[t*4];
                w.x -= l*x.x; w.y -= l*x.y; w.z -= l*x.z; w.w -= l*x.w;
            }
            *(float4*)(W + (size_t)(rrow+tid)*4) = w;
        }
    }
}

// ------------------------------------------------------------------
// Panel TRSM by substitution (no inverse) + W_s diag-solve block.
__global__ __launch_bounds__(256) void k_trsm2(float* __restrict__ A, float* __restrict__ W,
                                               const float* __restrict__ Z, int s){
    __shared__ float Ld[64*68];
    __shared__ float dinv[64];
    const int tid = threadIdx.x;
    const int s0  = s*64;
    // cooperative load of L11 = A[s0..+64][s0..+64]
#pragma unroll
    for (int it=0; it<4; ++it){
        int idx = tid + it*256;
        int r = idx>>4, q = idx&15;
        float4 v = *(const float4*)(A + (size_t)(s0+r)*LDA + s0 + q*4);
        *(float4*)&Ld[r*68 + q*4] = v;
    }
    __syncthreads();
    if (tid < 64) dinv[tid] = 1.0f/Ld[tid*68 + tid];
    __syncthreads();

    const int nRB = (63-s+3)>>2;        // 256-row tile blocks
    if ((int)blockIdx.x < nRB){
        const int row = s0 + 64 + blockIdx.x*256 + tid;
        const int rl  = row>4095 ? 4095 : row;
        float x[64];
        const float* src = A + (size_t)rl*LDA + s0;
#pragma unroll
        for (int q=0;q<16;q++){
            float4 v = *(const float4*)(src + q*4);
            x[q*4]=v.x; x[q*4+1]=v.y; x[q*4+2]=v.z; x[q*4+3]=v.w;
        }
#pragma unroll
        for (int c=0;c<64;c++){
            float xc = x[c]*dinv[c];
            x[c] = xc;
#pragma unroll
            for (int t=c+1;t<64;t++) x[t] -= xc*Ld[t*68 + c];
        }
        if (row < 4096){
            float* dst = A + (size_t)row*LDA + s0;
#pragma unroll
            for (int q=0;q<16;q++)
                *(float4*)(dst + q*4) = make_float4(x[q*4],x[q*4+1],x[q*4+2],x[q*4+3]);
        }
    } else {
        // W_s diag solve (wave 0)
        if (tid < 64){
            const int lane = tid;
            const float* wsrc = (s==0) ? (Z + (size_t)(s0+lane)*4) : (W + (size_t)(s0+lane)*4);
            float4 wv = *(const float4*)wsrc;
            float w0=wv.x, w1=wv.y, w2=wv.z, w3=wv.w;
#pragma unroll
            for (int j=0;j<64;j++){
                if (lane==j){ float dj=dinv[j]; w0*=dj; w1*=dj; w2*=dj; w3*=dj; }
                float b0=__shfl(w0,j), b1=__shfl(w1,j), b2=__shfl(w2,j), b3=__shfl(w3,j);
                float l = Ld[lane*68 + j];
                if (lane>j){ w0-=l*b0; w1-=l*b1; w2-=l*b2; w3-=l*b3; }
            }
            *(float4*)(W + (size_t)(s0+lane)*4) = make_float4(w0,w1,w2,w3);
        }
    }
}

// ------------------------------------------------------------------
__global__ void k_lossfit(const float* __restrict__ Z, const float* __restrict__ Y,
                          double* __restrict__ acc){
    const int tid=threadIdx.x;
    const int i0=blockIdx.x*8;
    double s=0.0;
    for (int ii=0;ii<8;ii++){
        const float4 zi = *(const float4*)(Z + (size_t)(i0+ii)*4);
        for (int j=tid;j<NN;j+=256){
            float4 zj = *(const float4*)(Z + (size_t)j*4);
            float4 yj = *(const float4*)(Y + (size_t)j*4);
            float d0=zi.x-zj.x, d1=zi.y-zj.y, d2=zi.z-zj.z, d3=zi.w-zj.w;
            float dzz = d0*d0+d1*d1+d2*d2+d3*d3;
            d0=zi.x-yj.x; d1=zi.y-yj.y; d2=zi.z-yj.z; d3=zi.w-yj.w;
            float dzy = d0*d0+d1*d1+d2*d2+d3*d3;
            s += (double)(__expf(-dzz) - 2.f*__expf(-dzy));
        }
    }
    for (int o=32;o;o>>=1) s += __shfl_down(s,o);
    __shared__ double ps[4];
    if ((tid&63)==0) ps[tid>>6]=s;
    __syncthreads();
    if (tid==0) atomicAdd(acc, ps[0]+ps[1]+ps[2]+ps[3]);
}

__global__ void k_zero(double* acc){ if (threadIdx.x==0) acc[0]=0.0; }

__global__ void k_finish(const float* __restrict__ W, const double* __restrict__ acc,
                         float* __restrict__ out){
    const int tid=threadIdx.x;
    double s=0.0;
    for (int r=tid;r<NN;r+=256){
        float4 v=*(const float4*)(W+(size_t)r*4);
        s += (double)v.x*v.x+(double)v.y*v.y+(double)v.z*v.z+(double)v.w*v.w;
    }
    for (int o=32;o;o>>=1) s += __shfl_down(s,o);
    __shared__ double ps[4];
    if ((tid&63)==0) ps[tid>>6]=s;
    __syncthreads();
    if (tid==0) out[0] = (float)(acc[0] + 0.01*(ps[0]+ps[1]+ps[2]+ps[3]));
}

// ------------------------------------------------------------------
extern "C" void kernel_launch(void* const* d_in, const int* in_sizes, int n_in,
                              void* d_out, int out_size, void* d_ws, size_t ws_size,
                              hipStream_t stream){
    const float* X=(const float*)d_in[0];
    const float* Y=(const float*)d_in[1];
    const float* Z=(const float*)d_in[2];
    float* ws   = (float*)d_ws;
    float* A    = ws;
    float* W    = ws + OFF_W;
    double* acc = (double*)((char*)d_ws + OFF_ACC_B);

    if (ws_size < OFF_ACC_B + 64) return;   // loud failure: output stays poisoned

    k_zero   <<<1,64,0,stream>>>(acc);
    k_lossfit<<<512,256,0,stream>>>(Z,Y,acc);
    k_build_A<<<dim3(NN/1024,NN),256,0,stream>>>(X,A);

    k_step<<<1,256,0,stream>>>(A,W,Z,-1);            // chol(0)
    for (int s=0;s<64;s++){
        const int T = 63-s;
        const int nRB = (T+3)>>2;
        k_trsm2<<<nRB+1,256,0,stream>>>(A,W,Z,s);
        if (s < 63){
            const int T2 = (T+1)>>1;
            const int nT2 = T2*(T2+1)/2;
            k_step<<<nT2+1+T,256,0,stream>>>(A,W,Z,s);
        }
    }
    k_finish<<<1,256,0,stream>>>(W,acc,(float*)d_out);
}

// Round 3
// 3476.950 us; speedup vs baseline: 2.3460x; 1.0043x over previous
//
#include <hip/hip_runtime.h>

// TransportKernel: loss = ||k_ZZ||_F^2 - 2||k_ZY||_F^2 + 0.01 * tr(Z^T (K_XX+1e-3 I)^{-1} Z)
// Cholesky A=LL^T with PB=256 outer panels; tr = ||L^{-1}Z||_F^2 (forward solve fused).
// Per outer step S: k_panel (single dispatch, flag-synced DAG over 64-row blocks)
//                   k_upd256 (rank-256 trailing SYRK, 128x128 tiles, K-chunked LDS)

#define NN 4096
#define LDA 4100
#define OFF_W     ((size_t)NN*LDA)
#define OFF_LINV  (OFF_W + (size_t)NN*4)
#define OFF_FLAGS (OFF_LINV + (size_t)4*4096)
#define OFF_ACC   (OFF_FLAGS + 512)

#define FD(S,i)   ((S)*4+(i))
#define FH(S,i,c) (64 + ((S)*4+(i))*4 + (c))

__device__ __forceinline__ float rdlane(float v, int l){
    return __int_as_float(__builtin_amdgcn_readlane(__float_as_int(v), l));
}
__device__ __forceinline__ void spin_flag(int* f, int idx){
    while (__hip_atomic_load(&f[idx], __ATOMIC_RELAXED, __HIP_MEMORY_SCOPE_AGENT) == 0)
        __builtin_amdgcn_s_sleep(8);
    __builtin_amdgcn_fence(__ATOMIC_ACQUIRE, "agent");
}
__device__ __forceinline__ void pub_flag(int* f, int idx){
    __syncthreads();
    if (threadIdx.x == 0)
        __hip_atomic_store(&f[idx], 1, __ATOMIC_RELEASE, __HIP_MEMORY_SCOPE_AGENT);
}

// ------------------------------------------------------------------
__global__ void k_build_A(const float* __restrict__ X, float* __restrict__ A){
    const int i  = blockIdx.y;
    const int j0 = (blockIdx.x*256 + threadIdx.x)*4;
    const float4 xi = *(const float4*)(X + (size_t)i*4);
    float out[4];
#pragma unroll
    for (int s=0;s<4;s++){
        const float4 xj = *(const float4*)(X + (size_t)(j0+s)*4);
        float d0=xi.x-xj.x, d1=xi.y-xj.y, d2=xi.z-xj.z, d3=xi.w-xj.w;
        float sq = d0*d0+d1*d1+d2*d2+d3*d3;
        float v  = __expf(-0.5f*sq);
        if (i == j0+s) v += 0.001f;
        out[s]=v;
    }
    *(float4*)(A + (size_t)i*LDA + j0) = make_float4(out[0],out[1],out[2],out[3]);
}

// ------------------------------------------------------------------
// Panel factorization for outer step S: cols [k0,k0+256), rows [k0,4096).
// Block j owns rows r0 = k0+64j .. +64. Heads j<4 produce diag/TRSM publishes.
__global__ __launch_bounds__(256) void k_panel(float* __restrict__ A, float* __restrict__ W,
                                               float* __restrict__ LinvTg, int* __restrict__ flags,
                                               int S){
    __shared__ float Po[64*68];     // transposed tile [t][r] / diag row-major La
    __shared__ float LiT[64*68];    // LinvT staging / head-tile staging / Li (row-major)
    __shared__ float LnT[64*68];    // own TRSM result transposed [t][r]
    __shared__ float Wi[64*4];
    __shared__ float Mt[16*17];
    const int tid = threadIdx.x;
    const int j   = blockIdx.x;
    const int k0  = S*256;
    const int r0  = k0 + j*64;
    const int tx = tid&15, ty = tid>>4;
    const bool head = (j < 4);
    const int nsteps = head ? j : 4;

    for (int i=0; i<nsteps; ++i){
        const int ci = k0 + i*64;
        spin_flag(flags, FD(S,i));
        __syncthreads();
        // stage own tile (j,i) transposed -> Po[t][r]; LinvT_i -> LiT[t][c]; W_i -> Wi
#pragma unroll
        for (int it=0; it<4; ++it){
            int idx = tid + it*256, r = idx>>4, q = idx&15;
            float4 v = *(const float4*)(A + (size_t)(r0+r)*LDA + ci + q*4);
            Po[(q*4+0)*68+r]=v.x; Po[(q*4+1)*68+r]=v.y;
            Po[(q*4+2)*68+r]=v.z; Po[(q*4+3)*68+r]=v.w;
            float4 u = *(const float4*)(LinvTg + (size_t)i*4096 + (size_t)idx*4);
            int t = idx>>4, c4 = (idx&15)*4;
            *(float4*)&LiT[t*68 + c4] = u;
        }
        if (tid < 64) *(float4*)&Wi[tid*4] = *(const float4*)(W + (size_t)(k0+i*64+tid)*4);
        __syncthreads();
        // TRSM as GEMM: Lnew[r][c] = sum_t Po[t][r]*LiT[t][c]
        float acc[4][4]={};
#pragma unroll 8
        for (int t=0;t<64;t++){
            float4 a = *(const float4*)&Po[t*68 + ty*4];
            float4 b = *(const float4*)&LiT[t*68 + tx*4];
            acc[0][0]+=a.x*b.x; acc[0][1]+=a.x*b.y; acc[0][2]+=a.x*b.z; acc[0][3]+=a.x*b.w;
            acc[1][0]+=a.y*b.x; acc[1][1]+=a.y*b.y; acc[1][2]+=a.y*b.z; acc[1][3]+=a.y*b.w;
            acc[2][0]+=a.z*b.x; acc[2][1]+=a.z*b.y; acc[2][2]+=a.z*b.z; acc[2][3]+=a.z*b.w;
            acc[3][0]+=a.w*b.x; acc[3][1]+=a.w*b.y; acc[3][2]+=a.w*b.z; acc[3][3]+=a.w*b.w;
        }
#pragma unroll
        for (int ii=0;ii<4;ii++)
            *(float4*)(A + (size_t)(r0+ty*4+ii)*LDA + ci + tx*4) =
                make_float4(acc[ii][0],acc[ii][1],acc[ii][2],acc[ii][3]);
#pragma unroll
        for (int ii=0;ii<4;ii++)
#pragma unroll
            for (int jj=0;jj<4;jj++)
                LnT[(tx*4+jj)*68 + ty*4+ii] = acc[ii][jj];
        if (head) pub_flag(flags, FH(S,i,j));      // includes __syncthreads
        else __syncthreads();
        // updates: tiles (j,c2), c2 in i+1..c2max
        const int c2max = head ? j : 3;
        for (int c2=i+1; c2<=c2max; ++c2){
            const float* Bsrc;
            if (c2 != j){
                spin_flag(flags, FH(S,i,c2));
                __syncthreads();
#pragma unroll
                for (int it=0; it<4; ++it){
                    int idx = tid + it*256, r = idx>>4, q = idx&15;
                    float4 v = *(const float4*)(A + (size_t)(k0+c2*64+r)*LDA + ci + q*4);
                    LiT[(q*4+0)*68+r]=v.x; LiT[(q*4+1)*68+r]=v.y;
                    LiT[(q*4+2)*68+r]=v.z; LiT[(q*4+3)*68+r]=v.w;
                }
                __syncthreads();
                Bsrc = LiT;
            } else {
                Bsrc = LnT;
            }
            float ua[4][4]={};
#pragma unroll 8
            for (int t=0;t<64;t++){
                float4 a = *(const float4*)&LnT[t*68 + ty*4];
                float4 b = *(const float4*)&Bsrc[t*68 + tx*4];
                ua[0][0]+=a.x*b.x; ua[0][1]+=a.x*b.y; ua[0][2]+=a.x*b.z; ua[0][3]+=a.x*b.w;
                ua[1][0]+=a.y*b.x; ua[1][1]+=a.y*b.y; ua[1][2]+=a.y*b.z; ua[1][3]+=a.y*b.w;
                ua[2][0]+=a.z*b.x; ua[2][1]+=a.z*b.y; ua[2][2]+=a.z*b.z; ua[2][3]+=a.z*b.w;
                ua[3][0]+=a.w*b.x; ua[3][1]+=a.w*b.y; ua[3][2]+=a.w*b.z; ua[3][3]+=a.w*b.w;
            }
#pragma unroll
            for (int ii=0;ii<4;ii++){
                float* p = A + (size_t)(r0+ty*4+ii)*LDA + k0+c2*64 + tx*4;
                float4 cv = *(float4*)p;
                cv.x-=ua[ii][0]; cv.y-=ua[ii][1]; cv.z-=ua[ii][2]; cv.w-=ua[ii][3];
                *(float4*)p = cv;
            }
        }
        // W update: W[r0+row][cw] -= sum_t LnT[t][row]*Wi[t][cw]
        {
            int row = tid>>2, cw = tid&3;
            float s = 0.f;
#pragma unroll 16
            for (int t=0;t<64;t++) s += LnT[t*68+row]*Wi[t*4+cw];
            float* wp = W + (size_t)(r0+row)*4 + cw;
            *wp = *wp - s;
        }
        __syncthreads();
    }

    if (head){
        const int ci = k0 + j*64;
        __syncthreads();
#pragma unroll
        for (int it=0; it<4; ++it){
            int idx = tid + it*256, r = idx>>4, q = idx&15;
            float4 v = *(const float4*)(A + (size_t)(r0+r)*LDA + ci + q*4);
            *(float4*)&Po[r*68 + q*4] = v;
        }
        __syncthreads();
        float row[64];
        if (tid < 64){
            const int lane = tid;
#pragma unroll
            for (int q=0;q<16;q++){
                float4 v = *(const float4*)&Po[lane*68 + q*4];
                row[q*4]=v.x; row[q*4+1]=v.y; row[q*4+2]=v.z; row[q*4+3]=v.w;
            }
#pragma unroll
            for (int jj=0;jj<64;jj++){
                float d  = rdlane(row[jj], jj);
                float sd = sqrtf(d);
                float inv= 1.0f/sd;
                float v  = (lane==jj)? sd : row[jj]*inv;
                row[jj] = v;
#pragma unroll
                for (int c=jj+1;c<64;c++){
                    float lc = rdlane(v, c);
                    row[c] -= v*lc;
                }
            }
            // write L to global and to Po (row-major) for inverse/solve
#pragma unroll
            for (int q=0;q<16;q++){
                float4 v = make_float4(row[q*4],row[q*4+1],row[q*4+2],row[q*4+3]);
                *(float4*)(A + (size_t)(r0+lane)*LDA + ci + q*4) = v;
                *(float4*)&Po[lane*68 + q*4] = v;
            }
        }
        __syncthreads();
        // ---- blocked triangular inverse of Po -> LiT (row-major Li) ----
        for (int idx=tid; idx<4096; idx+=256){
            int r = idx>>6, c = idx&63;
            if (r < c) LiT[r*68+c] = 0.f;
        }
        __syncthreads();
        {   // 16x16 diagonal-block inverses: 4 blocks x 16 cols x 4 lanes
            const int d = tid>>6, cc = (tid>>2)&15, g = tid&3;
            const int c = d*16 + cc, hi = (d+1)*16;
            for (int jj=c; jj<hi; ++jj){
                float part = 0.f;
                for (int t=c+g; t<jj; t+=4) part += Po[jj*68+t]*LiT[t*68+c];
                part += __shfl_xor(part,1);
                part += __shfl_xor(part,2);
                float x = ((jj==c)?1.f:0.f) - part;
                x /= Po[jj*68+jj];
                if (g==0) LiT[jj*68+c] = x;
            }
        }
        __syncthreads();
        {   // off-diag blocks by distance s: Linv[br][bc] = -Dinv_br * sum_k L[br][k] Linv[k][bc]
            const int r16 = tid>>4, c16 = tid&15;
            for (int sdist=1; sdist<4; ++sdist){
                for (int bc=0; bc+sdist<4; ++bc){
                    const int br = bc + sdist;
                    float m = 0.f;
                    for (int k=bc; k<br; ++k)
#pragma unroll 4
                        for (int t2=0;t2<16;t2++)
                            m += Po[(16*br+r16)*68 + 16*k+t2] * LiT[(16*k+t2)*68 + 16*bc+c16];
                    Mt[r16*17+c16] = m;
                    __syncthreads();
                    float x = 0.f;
#pragma unroll 4
                    for (int t=0;t<16;t++)
                        x += LiT[(16*br+r16)*68 + 16*br+t] * Mt[t*17+c16];
                    __syncthreads();
                    LiT[(16*br+r16)*68 + 16*bc+c16] = -x;
                    __syncthreads();
                }
            }
        }
        // store LinvT (t-major) to global
        for (int idx=tid; idx<4096; idx+=256){
            int t = idx>>6, c = idx&63;
            LinvTg[(size_t)j*4096 + idx] = LiT[c*68 + t];
        }
        // W diagonal solve by wave 0 using register rows
        if (tid < 64){
            const int lane = tid;
            float4 wv = *(const float4*)(W + (size_t)(r0+lane)*4);
            float w0=wv.x,w1=wv.y,w2=wv.z,w3=wv.w;
            const float myinv = 1.f/row[lane];
#pragma unroll
            for (int jj=0;jj<64;jj++){
                if (lane==jj){ w0*=myinv; w1*=myinv; w2*=myinv; w3*=myinv; }
                float b0=__shfl(w0,jj), b1=__shfl(w1,jj), b2=__shfl(w2,jj), b3=__shfl(w3,jj);
                float l = row[jj];
                if (lane>jj){ w0-=l*b0; w1-=l*b1; w2-=l*b2; w3-=l*b3; }
            }
            *(float4*)(W + (size_t)(r0+lane)*4) = make_float4(w0,w1,w2,w3);
        }
        pub_flag(flags, FD(S,j));
    }
}

// ------------------------------------------------------------------
// Rank-256 trailing update: A[r][c] -= sum_{t in panel} L[r][t]*L[c][t], 128x128 tiles.
__global__ __launch_bounds__(256) void k_upd256(float* __restrict__ A, int S){
    __shared__ float Sa[32*132];
    __shared__ float Sb[32*132];
    const int tid = threadIdx.x;
    const int k0 = S*256, base = k0+256;
    int t2 = blockIdx.x;
    int bi = (int)((sqrtf(8.f*(float)t2+1.f)-1.f)*0.5f);
    while ((bi+1)*(bi+2)/2 <= t2) ++bi;
    while (bi*(bi+1)/2 > t2) --bi;
    const int bj = t2 - bi*(bi+1)/2;
    const int r0 = base + bi*128, c0 = base + bj*128;
    const bool dg = (bi==bj);
    const float* Sbp = dg ? Sa : Sb;
    const int tx = tid&15, ty = tid>>4;
    int row_[4], q_[4];
#pragma unroll
    for (int it=0;it<4;++it){ int idx=tid+it*256; row_[it]=idx>>3; q_[it]=idx&7; }
    float4 ra[4], rb[4];
#pragma unroll
    for (int it=0;it<4;++it){
        ra[it] = *(const float4*)(A + (size_t)(r0+row_[it])*LDA + k0 + q_[it]*4);
        if (!dg) rb[it] = *(const float4*)(A + (size_t)(c0+row_[it])*LDA + k0 + q_[it]*4);
    }
    float acc[8][8]={};
    for (int kk=0;kk<8;++kk){
        __syncthreads();
#pragma unroll
        for (int it=0;it<4;++it){
            Sa[(q_[it]*4+0)*132+row_[it]]=ra[it].x; Sa[(q_[it]*4+1)*132+row_[it]]=ra[it].y;
            Sa[(q_[it]*4+2)*132+row_[it]]=ra[it].z; Sa[(q_[it]*4+3)*132+row_[it]]=ra[it].w;
            if (!dg){
                Sb[(q_[it]*4+0)*132+row_[it]]=rb[it].x; Sb[(q_[it]*4+1)*132+row_[it]]=rb[it].y;
                Sb[(q_[it]*4+2)*132+row_[it]]=rb[it].z; Sb[(q_[it]*4+3)*132+row_[it]]=rb[it].w;
            }
        }
        __syncthreads();
        if (kk < 7){
            const int kb = k0 + (kk+1)*32;
#pragma unroll
            for (int it=0;it<4;++it){
                ra[it] = *(const float4*)(A + (size_t)(r0+row_[it])*LDA + kb + q_[it]*4);
                if (!dg) rb[it] = *(const float4*)(A + (size_t)(c0+row_[it])*LDA + kb + q_[it]*4);
            }
        }
#pragma unroll 4
        for (int t=0;t<32;++t){
            float4 a0 = *(const float4*)&Sa[t*132 + ty*8];
            float4 a1 = *(const float4*)&Sa[t*132 + ty*8 + 4];
            float4 b0 = *(const float4*)&Sbp[t*132 + tx*8];
            float4 b1 = *(const float4*)&Sbp[t*132 + tx*8 + 4];
            float av[8]={a0.x,a0.y,a0.z,a0.w,a1.x,a1.y,a1.z,a1.w};
            float bv[8]={b0.x,b0.y,b0.z,b0.w,b1.x,b1.y,b1.z,b1.w};
#pragma unroll
            for (int i=0;i<8;i++)
#pragma unroll
                for (int jj=0;jj<8;jj++) acc[i][jj] += av[i]*bv[jj];
        }
    }
#pragma unroll
    for (int ii=0;ii<8;ii++){
        float* p = A + (size_t)(r0+ty*8+ii)*LDA + c0 + tx*8;
        float4 c1 = *(float4*)p;
        c1.x-=acc[ii][0]; c1.y-=acc[ii][1]; c1.z-=acc[ii][2]; c1.w-=acc[ii][3];
        *(float4*)p = c1;
        float4 c2 = *(float4*)(p+4);
        c2.x-=acc[ii][4]; c2.y-=acc[ii][5]; c2.z-=acc[ii][6]; c2.w-=acc[ii][7];
        *(float4*)(p+4) = c2;
    }
}

// ------------------------------------------------------------------
__global__ void k_lossfit(const float* __restrict__ Z, const float* __restrict__ Y,
                          double* __restrict__ acc){
    const int tid=threadIdx.x;
    const int i0=blockIdx.x*8;
    double s=0.0;
    for (int ii=0;ii<8;ii++){
        const float4 zi = *(const float4*)(Z + (size_t)(i0+ii)*4);
        for (int j=tid;j<NN;j+=256){
            float4 zj = *(const float4*)(Z + (size_t)j*4);
            float4 yj = *(const float4*)(Y + (size_t)j*4);
            float d0=zi.x-zj.x, d1=zi.y-zj.y, d2=zi.z-zj.z, d3=zi.w-zj.w;
            float dzz = d0*d0+d1*d1+d2*d2+d3*d3;
            d0=zi.x-yj.x; d1=zi.y-yj.y; d2=zi.z-yj.z; d3=zi.w-yj.w;
            float dzy = d0*d0+d1*d1+d2*d2+d3*d3;
            s += (double)(__expf(-dzz) - 2.f*__expf(-dzy));
        }
    }
    for (int o=32;o;o>>=1) s += __shfl_down(s,o);
    __shared__ double ps[4];
    if ((tid&63)==0) ps[tid>>6]=s;
    __syncthreads();
    if (tid==0) atomicAdd(acc, ps[0]+ps[1]+ps[2]+ps[3]);
}

__global__ void k_zero(double* acc, int* flags){
    if (threadIdx.x==0) acc[0]=0.0;
    if (threadIdx.x<512) flags[threadIdx.x]=0;
}

__global__ void k_copyZ(const float* __restrict__ Z, float* __restrict__ W){
    const int i = blockIdx.x*256+threadIdx.x;
    ((float4*)W)[i] = ((const float4*)Z)[i];
}

__global__ void k_finish(const float* __restrict__ W, const double* __restrict__ acc,
                         float* __restrict__ out){
    const int tid=threadIdx.x;
    double s=0.0;
    for (int r=tid;r<NN;r+=256){
        float4 v=*(const float4*)(W+(size_t)r*4);
        s += (double)v.x*v.x+(double)v.y*v.y+(double)v.z*v.z+(double)v.w*v.w;
    }
    for (int o=32;o;o>>=1) s += __shfl_down(s,o);
    __shared__ double ps[4];
    if ((tid&63)==0) ps[tid>>6]=s;
    __syncthreads();
    if (tid==0) out[0] = (float)(acc[0] + 0.01*(ps[0]+ps[1]+ps[2]+ps[3]));
}

// ------------------------------------------------------------------
extern "C" void kernel_launch(void* const* d_in, const int* in_sizes, int n_in,
                              void* d_out, int out_size, void* d_ws, size_t ws_size,
                              hipStream_t stream){
    const float* X=(const float*)d_in[0];
    const float* Y=(const float*)d_in[1];
    const float* Z=(const float*)d_in[2];
    float* ws    = (float*)d_ws;
    float* A     = ws;
    float* W     = ws + OFF_W;
    float* LinvT = ws + OFF_LINV;
    int*   flags = (int*)(ws + OFF_FLAGS);
    double* acc  = (double*)(ws + OFF_ACC);

    if (ws_size < (OFF_ACC + 4)*sizeof(float) + 16) return;  // loud failure

    k_zero   <<<1,512,0,stream>>>(acc, flags);
    k_copyZ  <<<16,256,0,stream>>>(Z, W);
    k_build_A<<<dim3(NN/1024,NN),256,0,stream>>>(X, A);
    k_lossfit<<<512,256,0,stream>>>(Z, Y, acc);

    for (int S=0; S<16; ++S){
        const int nblk = 64 - 4*S;
        k_panel<<<nblk,256,0,stream>>>(A, W, LinvT, flags, S);
        if (S < 15){
            const int T2 = 30 - 2*S;
            const int nT2 = T2*(T2+1)/2;
            k_upd256<<<nT2,256,0,stream>>>(A, S);
        }
    }
    k_finish<<<1,256,0,stream>>>(W, acc, (float*)d_out);
}